// Round 1
// baseline (6239.911 us; speedup 1.0000x reference)
//
#include <hip/hip_runtime.h>

#define CCH   256
#define BATCH 8
#define LFULL 4096
#define SKL   2050
#define TT    32

__device__ __forceinline__ float gatef(float h) {
  return tanhf(h) * (1.0f / (1.0f + expf(-h)));
}

// x[b,t,c] = in[b,t] * w[c] + b[c]
__global__ __launch_bounds__(256)
void causal_init(const float* __restrict__ in, const float* __restrict__ w,
                 const float* __restrict__ b, float* __restrict__ x) {
  int t = blockIdx.x, bb = blockIdx.y, c = threadIdx.x;
  float v = in[(size_t)bb * LFULL + t];
  x[((size_t)bb * LFULL + t) * CCH + c] = fmaf(v, w[c], b[c]);
}

enum { MODE_GATE = 0, MODE_RES = 1, MODE_SKIP = 2, MODE_PLAIN = 3 };

// Generic tiled [TT x 256] x [K(=256*TAPS) x 256] conv-GEMM with fused epilogue.
// Block: 256 threads = 4 waves; wave tg owns 8 t-rows; lane co owns 4 couts.
template <int TAPS, int MODE>
__global__ __launch_bounds__(256)
void convk(const float* __restrict__ Xin, long in_bstride, int inoff, int d,
           const float* __restrict__ W0, const float* __restrict__ W1,
           const float* __restrict__ bias, float* __restrict__ Out,
           long out_bstride, int Tout, float prescale) {
  __shared__ float xa[TT][CCH];
  __shared__ float xb[TAPS == 2 ? TT : 1][CCH];

  const int tid = threadIdx.x;
  const int bb  = blockIdx.y;
  const int t0  = blockIdx.x * TT;
  const float* Xb = Xin + (size_t)bb * in_bstride;

  // stage input rows [t0, t0+TT) (+d for tap 2) into LDS, coalesced float4
  for (int idx = tid; idx < TT * 64; idx += 256) {
    int r  = idx >> 6;
    int c4 = (idx & 63) << 2;
    int t  = t0 + r;
    if (t < Tout) {
      const float* p = Xb + (size_t)(t + inoff) * CCH + c4;
      float4 v = *(const float4*)p;
      if (MODE == MODE_PLAIN) {   // fused relu(in * prescale)
        v.x = fmaxf(v.x * prescale, 0.0f);
        v.y = fmaxf(v.y * prescale, 0.0f);
        v.z = fmaxf(v.z * prescale, 0.0f);
        v.w = fmaxf(v.w * prescale, 0.0f);
      }
      *(float4*)&xa[r][c4] = v;
      if constexpr (TAPS == 2) {
        float4 u = *(const float4*)(p + (size_t)d * CCH);
        *(float4*)&xb[r][c4] = u;
      }
    }
  }
  __syncthreads();

  const int co = (tid & 63) << 2;  // cout base (4 couts per lane)
  const int tg = tid >> 6;         // wave id -> 8 t rows

  float acc[8][4];
  float4 bv = *(const float4*)&bias[co];
  #pragma unroll
  for (int j = 0; j < 8; ++j) {
    acc[j][0] = bv.x; acc[j][1] = bv.y; acc[j][2] = bv.z; acc[j][3] = bv.w;
  }

  for (int ci = 0; ci < CCH; ++ci) {
    float4 w0 = *(const float4*)&W0[(size_t)ci * CCH + co];
    float4 w1 = {0.f, 0.f, 0.f, 0.f};
    if constexpr (TAPS == 2) w1 = *(const float4*)&W1[(size_t)ci * CCH + co];
    #pragma unroll
    for (int j = 0; j < 8; ++j) {
      float a = xa[tg * 8 + j][ci];
      acc[j][0] = fmaf(a, w0.x, acc[j][0]);
      acc[j][1] = fmaf(a, w0.y, acc[j][1]);
      acc[j][2] = fmaf(a, w0.z, acc[j][2]);
      acc[j][3] = fmaf(a, w0.w, acc[j][3]);
      if constexpr (TAPS == 2) {
        float b2 = xb[tg * 8 + j][ci];
        acc[j][0] = fmaf(b2, w1.x, acc[j][0]);
        acc[j][1] = fmaf(b2, w1.y, acc[j][1]);
        acc[j][2] = fmaf(b2, w1.z, acc[j][2]);
        acc[j][3] = fmaf(b2, w1.w, acc[j][3]);
      }
    }
  }

  float* Ob = Out + (size_t)bb * out_bstride;
  #pragma unroll
  for (int j = 0; j < 8; ++j) {
    int t = t0 + tg * 8 + j;
    if (t >= Tout) continue;
    float* op = Ob + (size_t)t * CCH + co;
    if constexpr (MODE == MODE_GATE) {
      float4 o;
      o.x = gatef(acc[j][0]); o.y = gatef(acc[j][1]);
      o.z = gatef(acc[j][2]); o.w = gatef(acc[j][3]);
      *(float4*)op = o;
    } else if constexpr (MODE == MODE_RES) {
      float4 o;
      o.x = acc[j][0] + xa[tg * 8 + j][co + 0];
      o.y = acc[j][1] + xa[tg * 8 + j][co + 1];
      o.z = acc[j][2] + xa[tg * 8 + j][co + 2];
      o.w = acc[j][3] + xa[tg * 8 + j][co + 3];
      *(float4*)op = o;
    } else if constexpr (MODE == MODE_SKIP) {
      float4 o = *(const float4*)op;
      o.x += acc[j][0]; o.y += acc[j][1]; o.z += acc[j][2]; o.w += acc[j][3];
      *(float4*)op = o;
    } else {  // MODE_PLAIN
      float4 o = {acc[j][0], acc[j][1], acc[j][2], acc[j][3]};
      *(float4*)op = o;
    }
  }
}

// One block per time step t: partial logits over k = t*256 .. t*256+255.
// part[t][b][n] = sum_ci f[b][t][ci] * W[(t*256+ci)*256 + n]
__global__ __launch_bounds__(256)
void dense_partial(const float* __restrict__ f, const float* __restrict__ W,
                   float* __restrict__ part) {
  int tstep = blockIdx.x;   // 0..2049
  int n = threadIdx.x;
  __shared__ float fs[BATCH][CCH];
  for (int idx = threadIdx.x; idx < BATCH * CCH; idx += 256) {
    int b = idx >> 8, c = idx & 255;
    fs[b][c] = f[((size_t)b * SKL + tstep) * CCH + c];
  }
  __syncthreads();
  float acc[BATCH] = {0.f, 0.f, 0.f, 0.f, 0.f, 0.f, 0.f, 0.f};
  const float* Wr = W + (size_t)tstep * CCH * CCH;
  for (int ci = 0; ci < CCH; ++ci) {
    float w = Wr[(size_t)ci * CCH + n];
    #pragma unroll
    for (int b = 0; b < BATCH; ++b) acc[b] = fmaf(fs[b][ci], w, acc[b]);
  }
  #pragma unroll
  for (int b = 0; b < BATCH; ++b)
    part[((size_t)tstep * BATCH + b) * CCH + n] = acc[b];
}

// tree-reduce the 2050 partials into 64 chunks per (b)
__global__ __launch_bounds__(256)
void reduce_part(const float* __restrict__ part, float* __restrict__ part2) {
  int chunk = blockIdx.x;  // 0..63
  int b = blockIdx.y;
  int n = threadIdx.x;
  int c0 = chunk * 33;
  int c1 = c0 + 33; if (c1 > SKL) c1 = SKL;
  float s = 0.f;
  for (int c = c0; c < c1; ++c) s += part[((size_t)c * BATCH + b) * CCH + n];
  part2[((size_t)b * 64 + chunk) * CCH + n] = s;
}

__global__ __launch_bounds__(256)
void softmax_k(const float* __restrict__ part2, const float* __restrict__ db,
               float* __restrict__ out) {
  int b = blockIdx.x;
  int n = threadIdx.x;
  float s = db[n];
  for (int ch = 0; ch < 64; ++ch) s += part2[((size_t)b * 64 + ch) * CCH + n];

  __shared__ float r4[4];
  __shared__ float mglob, sglob;
  int wid = n >> 6, lane = n & 63;

  float m = s;
  #pragma unroll
  for (int off = 1; off < 64; off <<= 1) m = fmaxf(m, __shfl_xor(m, off));
  if (lane == 0) r4[wid] = m;
  __syncthreads();
  if (n == 0) mglob = fmaxf(fmaxf(r4[0], r4[1]), fmaxf(r4[2], r4[3]));
  __syncthreads();

  float e = expf(s - mglob);
  float se = e;
  #pragma unroll
  for (int off = 1; off < 64; off <<= 1) se += __shfl_xor(se, off);
  if (lane == 0) r4[wid] = se;
  __syncthreads();
  if (n == 0) sglob = r4[0] + r4[1] + r4[2] + r4[3];
  __syncthreads();

  out[(size_t)b * CCH + n] = e / sglob;
}

extern "C" void kernel_launch(void* const* d_in, const int* in_sizes, int n_in,
                              void* d_out, int out_size, void* d_ws, size_t ws_size,
                              hipStream_t stream) {
  const float* input_x  = (const float*)d_in[0];
  const float* causal_w = (const float*)d_in[1];
  const float* causal_b = (const float*)d_in[2];
  const float* dil_w    = (const float*)d_in[3];
  const float* dil_b    = (const float*)d_in[4];
  const float* res_w    = (const float*)d_in[5];
  const float* res_b    = (const float*)d_in[6];
  const float* skip_w   = (const float*)d_in[7];
  const float* skip_b   = (const float*)d_in[8];
  const float* cls_w    = (const float*)d_in[9];
  const float* cls_b    = (const float*)d_in[10];
  const float* dense_w  = (const float*)d_in[11];
  const float* dense_b  = (const float*)d_in[12];
  float* out = (float*)d_out;

  // workspace layout (floats)
  float* X     = (float*)d_ws;                          // 8*4096*256
  float* G     = X + (size_t)BATCH * LFULL * CCH;       // 8*4096*256
  float* SKIPA = G + (size_t)BATCH * LFULL * CCH;       // 8*2050*256
  float* S1    = SKIPA + (size_t)BATCH * SKL * CCH;     // 8*2050*256
  float* S2    = S1 + (size_t)BATCH * SKL * CCH;        // 8*2050*256
  float* PART  = S2 + (size_t)BATCH * SKL * CCH;        // 2050*8*256
  float* PART2 = PART + (size_t)SKL * BATCH * CCH;      // 8*64*256

  const long xstride = (long)LFULL * CCH;
  const long sstride = (long)SKL * CCH;

  hipMemsetAsync(SKIPA, 0, (size_t)BATCH * SKL * CCH * sizeof(float), stream);

  dim3 blk(256);
  causal_init<<<dim3(LFULL, BATCH), blk, 0, stream>>>(input_x, causal_w, causal_b, X);

  static const int dil[20] = {1, 2, 4, 8, 16, 32, 64, 128, 256, 512,
                              1, 2, 4, 8, 16, 32, 64, 128, 256, 512};

  int T = LFULL;
  for (int i = 0; i < 20; ++i) {
    int d = dil[i];
    int Tout = T - d;
    int ntile = (Tout + TT - 1) / TT;

    // h = x[t]*W0 + x[t+d]*W1 + b ; g = tanh(h)*sigmoid(h)
    convk<2, MODE_GATE><<<dim3(ntile, BATCH), blk, 0, stream>>>(
        X, xstride, 0, d,
        dil_w + (size_t)(i * 2 + 0) * CCH * CCH,
        dil_w + (size_t)(i * 2 + 1) * CCH * CCH,
        dil_b + (size_t)i * CCH, G, xstride, Tout, 1.0f);

    // x = g @ res_w + res_b + g   (in place on X)
    convk<1, MODE_RES><<<dim3(ntile, BATCH), blk, 0, stream>>>(
        G, xstride, 0, 0,
        res_w + (size_t)i * CCH * CCH, nullptr,
        res_b + (size_t)i * CCH, X, xstride, Tout, 1.0f);

    // skip_acc += (g @ skip_w + skip_b)[:, -2050:]
    int off = Tout - SKL;
    int stile = (SKL + TT - 1) / TT;
    convk<1, MODE_SKIP><<<dim3(stile, BATCH), blk, 0, stream>>>(
        G, xstride, off, 0,
        skip_w + (size_t)i * CCH * CCH, nullptr,
        skip_b + (size_t)i * CCH, SKIPA, sstride, SKL, 1.0f);

    T = Tout;
  }

  // head: S1 = relu(skip_acc/20) @ cls_w + cls_b ; S2 = relu(S1) @ cls_w + cls_b
  int stile = (SKL + TT - 1) / TT;
  convk<1, MODE_PLAIN><<<dim3(stile, BATCH), blk, 0, stream>>>(
      SKIPA, sstride, 0, 0, cls_w, nullptr, cls_b, S1, sstride, SKL, 1.0f / 20.0f);
  convk<1, MODE_PLAIN><<<dim3(stile, BATCH), blk, 0, stream>>>(
      S1, sstride, 0, 0, cls_w, nullptr, cls_b, S2, sstride, SKL, 1.0f);

  // logits = f @ dense_w + dense_b ; softmax
  dense_partial<<<dim3(SKL), blk, 0, stream>>>(S2, dense_w, PART);
  reduce_part<<<dim3(64, BATCH), blk, 0, stream>>>(PART, PART2);
  softmax_k<<<dim3(BATCH), blk, 0, stream>>>(PART2, dense_b, out);
}

// Round 2
// 1664.280 us; speedup vs baseline: 3.7493x; 3.7493x over previous
//
#include <hip/hip_runtime.h>

typedef __attribute__((ext_vector_type(8))) short short8;
typedef __attribute__((ext_vector_type(4))) float f32x4;
typedef unsigned int uint32;
typedef unsigned short ushort16;

#define CCH   256
#define BATCH 8
#define LFULL 4096
#define SKL   2050
#define BM    128
#define BN    128
#define LDK   72   // padded LDS row stride in bf16 units (144 B)

__device__ __forceinline__ ushort16 f2b(float f) {
  uint32 u = __float_as_uint(f);
  u += 0x7fff + ((u >> 16) & 1);
  return (ushort16)(u >> 16);
}
__device__ __forceinline__ float b2f(ushort16 h) {
  return __uint_as_float(((uint32)h) << 16);
}
__device__ __forceinline__ float gatef(float h) {
  float hc = fmaxf(h, -30.0f);
  float q = __expf(-hc);
  return (1.0f - q) / (1.0f + q * q);
}

// ---------------- weight packing: fp32 [..][ci][co] -> bf16 [..][co][k] ----
__global__ __launch_bounds__(256)
void pack_dil(const float* __restrict__ w, ushort16* __restrict__ o) {
  int e = blockIdx.x * 256 + threadIdx.x;           // ((i*2+tap)*256+ci)*256+co
  int co = e & 255, ci = (e >> 8) & 255, tap = (e >> 16) & 1, i = e >> 17;
  o[((size_t)(i * 256 + co)) * 512 + tap * 256 + ci] = f2b(w[e]);
}
__global__ __launch_bounds__(256)
void pack_sq(const float* __restrict__ w, ushort16* __restrict__ o) {
  int e = blockIdx.x * 256 + threadIdx.x;           // (i*256+ci)*256+co
  int co = e & 255, ci = (e >> 8) & 255, i = e >> 16;
  o[((size_t)(i * 256 + co)) * 256 + ci] = f2b(w[e]);
}

// x[b,t,c] = bf16(in[b,t] * w[c] + b[c])
__global__ __launch_bounds__(256)
void causal_init(const float* __restrict__ in, const float* __restrict__ w,
                 const float* __restrict__ b, ushort16* __restrict__ x) {
  int t = blockIdx.x, bb = blockIdx.y, c = threadIdx.x;
  float v = in[(size_t)bb * LFULL + t];
  x[((size_t)bb * LFULL + t) * CCH + c] = f2b(fmaf(v, w[c], b[c]));
}

enum { MODE_GATE = 0, MODE_RES = 1, MODE_SKIP = 2, MODE_CLS1 = 3, MODE_CLS2 = 4 };

// MFMA conv-GEMM: out[t][n] = A[t(+tap*d)][k] @ Wt[n][k] + bias, fused epilogue.
// 256 thr = 4 waves (2x2), each wave 64x64 out = 4x4 16x16x32 fragments.
template <int TAPS, int MODE>
__global__ __launch_bounds__(256)
void convm(const void* __restrict__ Ainv, long a_bstride, int inoff, int d,
           const ushort16* __restrict__ Wt, const float* __restrict__ bias,
           void* __restrict__ Out1, long out_bstride, int Tout) {
  __shared__ ushort16 As[BM * LDK];
  __shared__ ushort16 Bs[BN * LDK];

  const int tid = threadIdx.x;
  const int bb  = blockIdx.z;
  const int t0  = blockIdx.x * BM;
  const int n0  = blockIdx.y * BN;
  const int lane = tid & 63, wv = tid >> 6;
  const int wm = wv >> 1, wn = wv & 1;
  const int fr = lane & 15, fq = lane >> 4;

  f32x4 acc[4][4];
  #pragma unroll
  for (int fn = 0; fn < 4; ++fn) {
    float bv = bias[n0 + wn * 64 + fn * 16 + fr];
    #pragma unroll
    for (int fm = 0; fm < 4; ++fm) acc[fm][fn] = (f32x4){bv, bv, bv, bv};
  }

  const int KTILES = TAPS * 4;
  for (int kt = 0; kt < KTILES; ++kt) {
    // ---- stage A tile [128 rows][64 k] ----
    for (int idx = tid; idx < 1024; idx += 256) {
      int r = idx >> 3, c8 = idx & 7;
      int t = t0 + r; if (t > Tout - 1) t = Tout - 1;
      uint4 v;
      if constexpr (MODE == MODE_CLS1) {
        const float* sp = (const float*)Ainv + (size_t)bb * a_bstride +
                          (size_t)(t + inoff) * CCH + kt * 64 + c8 * 8;
        ushort16 tmp[8];
        #pragma unroll
        for (int j = 0; j < 8; ++j)
          tmp[j] = f2b(fmaxf(sp[j] * (1.0f / 20.0f), 0.0f));
        v = *(uint4*)tmp;
      } else if constexpr (MODE == MODE_CLS2) {
        const ushort16* sp = (const ushort16*)Ainv + (size_t)bb * a_bstride +
                             (size_t)(t + inoff) * CCH + kt * 64 + c8 * 8;
        ushort16 tmp[8];
        #pragma unroll
        for (int j = 0; j < 8; ++j) {
          ushort16 h = sp[j];
          tmp[j] = (h & 0x8000) ? (ushort16)0 : h;   // relu in bf16
        }
        v = *(uint4*)tmp;
      } else {
        int trow, ksrc;
        if constexpr (TAPS == 2) {
          int tap = kt >> 2;
          trow = t + inoff + tap * d;
          ksrc = (kt & 3) * 64 + c8 * 8;
        } else {
          trow = t + inoff;
          ksrc = kt * 64 + c8 * 8;
        }
        const ushort16* sp = (const ushort16*)Ainv + (size_t)bb * a_bstride +
                             (size_t)trow * CCH + ksrc;
        v = *(const uint4*)sp;
      }
      *(uint4*)&As[r * LDK + c8 * 8] = v;
    }
    // ---- stage B tile: Wt[n0+r][kt*64 + ...] ----
    for (int idx = tid; idx < 1024; idx += 256) {
      int r = idx >> 3, c8 = idx & 7;
      const ushort16* sp = Wt + (size_t)(n0 + r) * (TAPS * 256) + kt * 64 + c8 * 8;
      *(uint4*)&Bs[r * LDK + c8 * 8] = *(const uint4*)sp;
    }
    __syncthreads();

    #pragma unroll
    for (int ks = 0; ks < 2; ++ks) {
      short8 af[4], bfr[4];
      #pragma unroll
      for (int fm = 0; fm < 4; ++fm)
        af[fm] = *(const short8*)&As[(wm * 64 + fm * 16 + fr) * LDK + ks * 32 + fq * 8];
      #pragma unroll
      for (int fn = 0; fn < 4; ++fn)
        bfr[fn] = *(const short8*)&Bs[(wn * 64 + fn * 16 + fr) * LDK + ks * 32 + fq * 8];
      #pragma unroll
      for (int fm = 0; fm < 4; ++fm)
        #pragma unroll
        for (int fn = 0; fn < 4; ++fn)
          acc[fm][fn] = __builtin_amdgcn_mfma_f32_16x16x32_bf16(
              af[fm], bfr[fn], acc[fm][fn], 0, 0, 0);
    }
    __syncthreads();
  }

  // ---- epilogue: D element (row = t0+wm*64+fm*16+fq*4+r, col = n0+wn*64+fn*16+fr)
  #pragma unroll
  for (int fm = 0; fm < 4; ++fm) {
    int rbase = t0 + wm * 64 + fm * 16 + fq * 4;
    #pragma unroll
    for (int r = 0; r < 4; ++r) {
      int t = rbase + r;
      if (t >= Tout) continue;
      #pragma unroll
      for (int fn = 0; fn < 4; ++fn) {
        int c = n0 + wn * 64 + fn * 16 + fr;
        float a = acc[fm][fn][r];
        size_t oix = (size_t)bb * out_bstride + (size_t)t * CCH + c;
        if constexpr (MODE == MODE_GATE) {
          ((ushort16*)Out1)[oix] = f2b(gatef(a));
        } else if constexpr (MODE == MODE_RES) {
          float g = b2f(((const ushort16*)Ainv)[(size_t)bb * a_bstride +
                                                (size_t)t * CCH + c]);
          ((ushort16*)Out1)[oix] = f2b(a + g);
        } else if constexpr (MODE == MODE_SKIP) {
          float* p = (float*)Out1 + oix;
          *p += a;
        } else if constexpr (MODE == MODE_CLS1) {
          ((ushort16*)Out1)[oix] = f2b(a);
        } else {  // MODE_CLS2
          ((float*)Out1)[oix] = a;
        }
      }
    }
  }
}

// ---------------- dense head (fp32, memory-bound on 537MB weights) --------
__global__ __launch_bounds__(256)
void dense_partial(const float* __restrict__ f, const float* __restrict__ W,
                   float* __restrict__ part) {
  int tstep = blockIdx.x;
  int n = threadIdx.x;
  __shared__ float fs[BATCH][CCH];
  for (int idx = threadIdx.x; idx < BATCH * CCH; idx += 256) {
    int b = idx >> 8, c = idx & 255;
    fs[b][c] = f[((size_t)b * SKL + tstep) * CCH + c];
  }
  __syncthreads();
  float acc[BATCH] = {0.f, 0.f, 0.f, 0.f, 0.f, 0.f, 0.f, 0.f};
  const float* Wr = W + (size_t)tstep * CCH * CCH;
  for (int ci = 0; ci < CCH; ++ci) {
    float w = Wr[(size_t)ci * CCH + n];
    #pragma unroll
    for (int b = 0; b < BATCH; ++b) acc[b] = fmaf(fs[b][ci], w, acc[b]);
  }
  #pragma unroll
  for (int b = 0; b < BATCH; ++b)
    part[((size_t)tstep * BATCH + b) * CCH + n] = acc[b];
}

__global__ __launch_bounds__(256)
void reduce_part(const float* __restrict__ part, float* __restrict__ part2) {
  int chunk = blockIdx.x, b = blockIdx.y, n = threadIdx.x;
  int c0 = chunk * 33;
  int c1 = c0 + 33; if (c1 > SKL) c1 = SKL;
  float s = 0.f;
  for (int c = c0; c < c1; ++c) s += part[((size_t)c * BATCH + b) * CCH + n];
  part2[((size_t)b * 64 + chunk) * CCH + n] = s;
}

__global__ __launch_bounds__(256)
void softmax_k(const float* __restrict__ part2, const float* __restrict__ db,
               float* __restrict__ out) {
  int b = blockIdx.x, n = threadIdx.x;
  float s = db[n];
  for (int ch = 0; ch < 64; ++ch) s += part2[((size_t)b * 64 + ch) * CCH + n];

  __shared__ float r4[4];
  __shared__ float mglob, sglob;
  int wid = n >> 6, lane = n & 63;

  float m = s;
  #pragma unroll
  for (int off = 1; off < 64; off <<= 1) m = fmaxf(m, __shfl_xor(m, off));
  if (lane == 0) r4[wid] = m;
  __syncthreads();
  if (n == 0) mglob = fmaxf(fmaxf(r4[0], r4[1]), fmaxf(r4[2], r4[3]));
  __syncthreads();

  float e = expf(s - mglob);
  float se = e;
  #pragma unroll
  for (int off = 1; off < 64; off <<= 1) se += __shfl_xor(se, off);
  if (lane == 0) r4[wid] = se;
  __syncthreads();
  if (n == 0) sglob = r4[0] + r4[1] + r4[2] + r4[3];
  __syncthreads();

  out[(size_t)b * CCH + n] = e / sglob;
}

extern "C" void kernel_launch(void* const* d_in, const int* in_sizes, int n_in,
                              void* d_out, int out_size, void* d_ws, size_t ws_size,
                              hipStream_t stream) {
  const float* input_x  = (const float*)d_in[0];
  const float* causal_w = (const float*)d_in[1];
  const float* causal_b = (const float*)d_in[2];
  const float* dil_w    = (const float*)d_in[3];
  const float* dil_b    = (const float*)d_in[4];
  const float* res_w    = (const float*)d_in[5];
  const float* res_b    = (const float*)d_in[6];
  const float* skip_w   = (const float*)d_in[7];
  const float* skip_b   = (const float*)d_in[8];
  const float* cls_w    = (const float*)d_in[9];
  const float* cls_b    = (const float*)d_in[10];
  const float* dense_w  = (const float*)d_in[11];
  const float* dense_b  = (const float*)d_in[12];
  float* out = (float*)d_out;

  // ---- workspace layout ----
  char* p = (char*)d_ws;
  ushort16* Xb  = (ushort16*)p; p += (size_t)BATCH * LFULL * CCH * 2;
  ushort16* G   = (ushort16*)p; p += (size_t)BATCH * LFULL * CCH * 2;
  float*  SKIPA = (float*)p;    p += (size_t)BATCH * SKL * CCH * 4;
  ushort16* S1  = (ushort16*)p; p += (size_t)BATCH * SKL * CCH * 2;
  float*  S2    = (float*)p;    p += (size_t)BATCH * SKL * CCH * 4;
  float*  PART  = (float*)p;    p += (size_t)SKL * BATCH * CCH * 4;
  float*  PART2 = (float*)p;    p += (size_t)BATCH * 64 * CCH * 4;
  ushort16* DW  = (ushort16*)p; p += (size_t)20 * 256 * 512 * 2;
  ushort16* RW  = (ushort16*)p; p += (size_t)20 * 256 * 256 * 2;
  ushort16* SW  = (ushort16*)p; p += (size_t)20 * 256 * 256 * 2;
  ushort16* CW  = (ushort16*)p; p += (size_t)256 * 256 * 2;

  const long xstride = (long)LFULL * CCH;
  const long sstride = (long)SKL * CCH;
  dim3 blk(256);

  // pack weights to bf16 transposed [n][k]
  pack_dil<<<dim3(20 * 2 * 256), blk, 0, stream>>>(dil_w, DW);
  pack_sq <<<dim3(20 * 256),     blk, 0, stream>>>(res_w, RW);
  pack_sq <<<dim3(20 * 256),     blk, 0, stream>>>(skip_w, SW);
  pack_sq <<<dim3(256),          blk, 0, stream>>>(cls_w, CW);

  hipMemsetAsync(SKIPA, 0, (size_t)BATCH * SKL * CCH * 4, stream);
  causal_init<<<dim3(LFULL, BATCH), blk, 0, stream>>>(input_x, causal_w, causal_b, Xb);

  static const int dil[20] = {1, 2, 4, 8, 16, 32, 64, 128, 256, 512,
                              1, 2, 4, 8, 16, 32, 64, 128, 256, 512};

  int T = LFULL;
  for (int i = 0; i < 20; ++i) {
    int d = dil[i];
    int Tout = T - d;
    int ntile = (Tout + BM - 1) / BM;
    int stile = (SKL + BM - 1) / BM;

    convm<2, MODE_GATE><<<dim3(ntile, 2, BATCH), blk, 0, stream>>>(
        Xb, xstride, 0, d, DW + (size_t)i * 256 * 512,
        dil_b + (size_t)i * CCH, G, xstride, Tout);

    convm<1, MODE_RES><<<dim3(ntile, 2, BATCH), blk, 0, stream>>>(
        G, xstride, 0, 0, RW + (size_t)i * 256 * 256,
        res_b + (size_t)i * CCH, Xb, xstride, Tout);

    convm<1, MODE_SKIP><<<dim3(stile, 2, BATCH), blk, 0, stream>>>(
        G, xstride, Tout - SKL, 0, SW + (size_t)i * 256 * 256,
        skip_b + (size_t)i * CCH, SKIPA, sstride, SKL);

    T = Tout;
  }

  int stile = (SKL + BM - 1) / BM;
  convm<1, MODE_CLS1><<<dim3(stile, 2, BATCH), blk, 0, stream>>>(
      SKIPA, sstride, 0, 0, CW, cls_b, S1, sstride, SKL);
  convm<1, MODE_CLS2><<<dim3(stile, 2, BATCH), blk, 0, stream>>>(
      S1, sstride, 0, 0, CW, cls_b, S2, sstride, SKL);

  dense_partial<<<dim3(SKL), blk, 0, stream>>>(S2, dense_w, PART);
  reduce_part<<<dim3(64, BATCH), blk, 0, stream>>>(PART, PART2);
  softmax_k<<<dim3(BATCH), blk, 0, stream>>>(PART2, dense_b, out);
}

// Round 3
// 1060.573 us; speedup vs baseline: 5.8835x; 1.5692x over previous
//
#include <hip/hip_runtime.h>

typedef __attribute__((ext_vector_type(8))) short short8;
typedef __attribute__((ext_vector_type(4))) float f32x4;
typedef unsigned int uint32;
typedef unsigned short u16;

#define CCH   256
#define BATCH 8
#define LFULL 4096
#define SKL   2050
#define BM    128
#define BN    128
#define LDK   72   // padded LDS row stride (bf16 units)

#define GSTRIDE ((size_t)BATCH * LFULL * CCH)  // elems per G(i) buffer
#define XSTR    ((size_t)LFULL * CCH)          // per-batch stride in G
#define SSTR    ((size_t)SKL * CCH)            // per-batch stride in P/S buffers
#define PSTR    ((size_t)BATCH * SKL * CCH)    // per-split stride in P

__device__ const int TOUT[20] = {4095,4093,4089,4081,4065,4033,3969,3841,3585,3073,
                                 3072,3070,3066,3058,3042,3010,2946,2818,2562,2050};

__device__ __forceinline__ u16 f2b(float f) {
  uint32 u = __float_as_uint(f);
  u += 0x7fff + ((u >> 16) & 1);
  return (u16)(u >> 16);
}
__device__ __forceinline__ float gatef(float h) {
  float hc = fmaxf(h, -30.0f);
  float q = __expf(-hc);
  return (1.0f - q) / (1.0f + q * q);   // tanh(h)*sigmoid(h)
}

// ---- compose W'_i = (R_{i-1} + I) @ W_i,tap  -> bf16 [bi][co][tap*256+ci] ----
__global__ __launch_bounds__(256)
void compose_w(const float* __restrict__ res_w, const float* __restrict__ dil_w,
               u16* __restrict__ DWc) {
  __shared__ float As[32][256];
  int bx = blockIdx.x;
  int chunk = bx & 7, tap = (bx >> 3) & 1, bi = bx >> 4;  // bi 0..18 -> block i=bi+1
  int i = bi + 1;
  int co = threadIdx.x;
  int ci0 = chunk * 32;

  for (int idx = threadIdx.x; idx < 32 * 256; idx += 256) {
    int r = idx >> 8, m = idx & 255;
    float v = res_w[((size_t)(bi * 256 + ci0 + r)) * 256 + m];
    if (ci0 + r == m) v += 1.0f;
    As[r][m] = v;
  }
  __syncthreads();

  float acc[32];
  #pragma unroll
  for (int r = 0; r < 32; ++r) acc[r] = 0.0f;

  const float* Wb = dil_w + ((size_t)(i * 2 + tap) * 256) * 256 + co;
  for (int m4 = 0; m4 < 64; ++m4) {
    const float* wp = Wb + (size_t)m4 * 4 * 256;
    float w0 = wp[0], w1 = wp[256], w2 = wp[512], w3 = wp[768];
    #pragma unroll
    for (int r = 0; r < 32; ++r) {
      float4 a = *(const float4*)&As[r][m4 * 4];
      acc[r] = fmaf(a.x, w0, acc[r]);
      acc[r] = fmaf(a.y, w1, acc[r]);
      acc[r] = fmaf(a.z, w2, acc[r]);
      acc[r] = fmaf(a.w, w3, acc[r]);
    }
  }
  u16* op = DWc + ((size_t)(bi * 256 + co)) * 512 + tap * 256 + ci0;
  #pragma unroll
  for (int r = 0; r < 32; ++r) op[r] = f2b(acc[r]);
}

// ---- b'_i = rb_{i-1} @ (W0_i + W1_i) + db_i  (fp32) ----
__global__ __launch_bounds__(256)
void compose_bias(const float* __restrict__ res_b, const float* __restrict__ dil_w,
                  const float* __restrict__ dil_b, float* __restrict__ Bc) {
  int bi = blockIdx.x, i = bi + 1, co = threadIdx.x;
  float acc = dil_b[(size_t)i * 256 + co];
  const float* W0 = dil_w + ((size_t)(i * 2 + 0) * 256) * 256;
  const float* W1 = dil_w + ((size_t)(i * 2 + 1) * 256) * 256;
  for (int m = 0; m < 256; ++m) {
    float rb = res_b[(size_t)bi * 256 + m];
    acc = fmaf(rb, W0[(size_t)m * 256 + co] + W1[(size_t)m * 256 + co], acc);
  }
  Bc[(size_t)bi * 256 + co] = acc;
}

// ---- block-0 rank-1 fold: u_tap = cw @ W0_tap, b0 = cb@(W00+W01)+db0 ----
__global__ __launch_bounds__(256)
void head0(const float* __restrict__ causal_w, const float* __restrict__ causal_b,
           const float* __restrict__ dil_w, const float* __restrict__ dil_b,
           float* __restrict__ U) {
  int co = threadIdx.x;
  float u0 = 0.f, u1 = 0.f, b0 = dil_b[co];
  for (int m = 0; m < 256; ++m) {
    float cwm = causal_w[m], cbm = causal_b[m];
    float w0 = dil_w[(size_t)m * 256 + co];
    float w1 = dil_w[(size_t)(256 + m) * 256 + co];
    u0 = fmaf(cwm, w0, u0);
    u1 = fmaf(cwm, w1, u1);
    b0 = fmaf(cbm, w0 + w1, b0);
  }
  U[co] = u0; U[256 + co] = u1; U[512 + co] = b0;
}

// ---- G0[b][t][c] = gate(in[t]*u0 + in[t+1]*u1 + b0) ----
__global__ __launch_bounds__(256)
void g0_init(const float* __restrict__ in, const float* __restrict__ U,
             u16* __restrict__ G0) {
  int t = blockIdx.x, b = blockIdx.y, co = threadIdx.x;
  float x0 = in[(size_t)b * LFULL + t];
  float x1 = in[(size_t)b * LFULL + t + 1];
  float h = fmaf(x0, U[co], fmaf(x1, U[256 + co], U[512 + co]));
  G0[((size_t)b * LFULL + t) * CCH + co] = f2b(gatef(h));
}

// ---- weight packs ----
__global__ __launch_bounds__(256)
void pack_skipT(const float* __restrict__ w, u16* __restrict__ o) {
  int e = blockIdx.x * 256 + threadIdx.x;   // (i*256+ci)*256+co
  int co = e & 255, ci = (e >> 8) & 255, i = e >> 16;
  o[(size_t)co * 5120 + i * 256 + ci] = f2b(w[e]);
}
__global__ __launch_bounds__(256)
void pack_cls(const float* __restrict__ w, u16* __restrict__ o) {
  int e = blockIdx.x * 256 + threadIdx.x;   // ci*256+co
  int co = e & 255, ci = e >> 8;
  o[(size_t)co * 256 + ci] = f2b(w[e]);
}
__global__ __launch_bounds__(256)
void sbsum_k(const float* __restrict__ sb, float* __restrict__ o) {
  int n = threadIdx.x;
  float s = 0.f;
  for (int i = 0; i < 20; ++i) s += sb[(size_t)i * 256 + n];
  o[n] = s;
}

enum { MODE_GATE = 0, MODE_CLS1 = 1, MODE_CLS2 = 2 };

// MFMA GEMM: out[t][n] = A[t(+tap*d)][k] @ Wt[n][k] + bias, fused epilogues.
template <int TAPS, int MODE>
__global__ __launch_bounds__(256)
void convm(const void* __restrict__ Ainv, long a_bstride, int d,
           const u16* __restrict__ Wt, const float* __restrict__ bias,
           const float* __restrict__ extra,
           void* __restrict__ Out1, long out_bstride, int Tout) {
  __shared__ u16 As[BM * LDK];
  __shared__ u16 Bs[BN * LDK];

  const int tid = threadIdx.x;
  const int bb  = blockIdx.z;
  const int t0  = blockIdx.x * BM;
  const int n0  = blockIdx.y * BN;
  const int lane = tid & 63, wv = tid >> 6;
  const int wm = wv >> 1, wn = wv & 1;
  const int fr = lane & 15, fq = lane >> 4;

  f32x4 acc[4][4];
  #pragma unroll
  for (int fn = 0; fn < 4; ++fn) {
    float bv = bias[n0 + wn * 64 + fn * 16 + fr];
    #pragma unroll
    for (int fm = 0; fm < 4; ++fm) acc[fm][fn] = (f32x4){bv, bv, bv, bv};
  }

  const int KTILES = TAPS * 4;
  for (int kt = 0; kt < KTILES; ++kt) {
    for (int idx = tid; idx < 1024; idx += 256) {
      int r = idx >> 3, c8 = idx & 7;
      int t = t0 + r; if (t > Tout - 1) t = Tout - 1;
      uint4 v;
      if constexpr (MODE == MODE_CLS1) {
        // A = relu((P0+P1+P2+P3 + sbsum) / 20), fp32 -> bf16
        const float* p0 = (const float*)Ainv + (size_t)bb * a_bstride +
                          (size_t)t * CCH + kt * 64 + c8 * 8;
        float4 s0 = *(const float4*)p0;
        float4 s1 = *(const float4*)(p0 + 4);
        #pragma unroll
        for (int j = 1; j < 4; ++j) {
          const float* pj = p0 + (size_t)j * PSTR;
          float4 a0 = *(const float4*)pj;
          float4 a1 = *(const float4*)(pj + 4);
          s0.x += a0.x; s0.y += a0.y; s0.z += a0.z; s0.w += a0.w;
          s1.x += a1.x; s1.y += a1.y; s1.z += a1.z; s1.w += a1.w;
        }
        float4 e0 = *(const float4*)&extra[kt * 64 + c8 * 8];
        float4 e1 = *(const float4*)&extra[kt * 64 + c8 * 8 + 4];
        u16 tmp[8];
        tmp[0] = f2b(fmaxf((s0.x + e0.x) * 0.05f, 0.f));
        tmp[1] = f2b(fmaxf((s0.y + e0.y) * 0.05f, 0.f));
        tmp[2] = f2b(fmaxf((s0.z + e0.z) * 0.05f, 0.f));
        tmp[3] = f2b(fmaxf((s0.w + e0.w) * 0.05f, 0.f));
        tmp[4] = f2b(fmaxf((s1.x + e1.x) * 0.05f, 0.f));
        tmp[5] = f2b(fmaxf((s1.y + e1.y) * 0.05f, 0.f));
        tmp[6] = f2b(fmaxf((s1.z + e1.z) * 0.05f, 0.f));
        tmp[7] = f2b(fmaxf((s1.w + e1.w) * 0.05f, 0.f));
        v = *(uint4*)tmp;
      } else if constexpr (MODE == MODE_CLS2) {
        const u16* sp = (const u16*)Ainv + (size_t)bb * a_bstride +
                        (size_t)t * CCH + kt * 64 + c8 * 8;
        uint4 raw = *(const uint4*)sp;
        u16 tmp[8];
        *(uint4*)tmp = raw;
        #pragma unroll
        for (int j = 0; j < 8; ++j) tmp[j] = (tmp[j] & 0x8000) ? (u16)0 : tmp[j];
        v = *(uint4*)tmp;
      } else {  // MODE_GATE, TAPS==2
        int tap = kt >> 2;
        int trow = t + tap * d;
        int ksrc = (kt & 3) * 64 + c8 * 8;
        const u16* sp = (const u16*)Ainv + (size_t)bb * a_bstride +
                        (size_t)trow * CCH + ksrc;
        v = *(const uint4*)sp;
      }
      *(uint4*)&As[r * LDK + c8 * 8] = v;
    }
    for (int idx = tid; idx < 1024; idx += 256) {
      int r = idx >> 3, c8 = idx & 7;
      const u16* sp = Wt + (size_t)(n0 + r) * (TAPS * 256) + kt * 64 + c8 * 8;
      *(uint4*)&Bs[r * LDK + c8 * 8] = *(const uint4*)sp;
    }
    __syncthreads();

    #pragma unroll
    for (int ks = 0; ks < 2; ++ks) {
      short8 af[4], bfr[4];
      #pragma unroll
      for (int fm = 0; fm < 4; ++fm)
        af[fm] = *(const short8*)&As[(wm * 64 + fm * 16 + fr) * LDK + ks * 32 + fq * 8];
      #pragma unroll
      for (int fn = 0; fn < 4; ++fn)
        bfr[fn] = *(const short8*)&Bs[(wn * 64 + fn * 16 + fr) * LDK + ks * 32 + fq * 8];
      #pragma unroll
      for (int fm = 0; fm < 4; ++fm)
        #pragma unroll
        for (int fn = 0; fn < 4; ++fn)
          acc[fm][fn] = __builtin_amdgcn_mfma_f32_16x16x32_bf16(
              af[fm], bfr[fn], acc[fm][fn], 0, 0, 0);
    }
    __syncthreads();
  }

  #pragma unroll
  for (int fm = 0; fm < 4; ++fm) {
    int rbase = t0 + wm * 64 + fm * 16 + fq * 4;
    #pragma unroll
    for (int r = 0; r < 4; ++r) {
      int t = rbase + r;
      if (t >= Tout) continue;
      #pragma unroll
      for (int fn = 0; fn < 4; ++fn) {
        int c = n0 + wn * 64 + fn * 16 + fr;
        float a = acc[fm][fn][r];
        size_t oix = (size_t)bb * out_bstride + (size_t)t * CCH + c;
        if constexpr (MODE == MODE_GATE) {
          ((u16*)Out1)[oix] = f2b(gatef(a));
        } else if constexpr (MODE == MODE_CLS1) {
          ((u16*)Out1)[oix] = f2b(a);
        } else {
          ((float*)Out1)[oix] = a;
        }
      }
    }
  }
}

// ---- deferred-skip mega-GEMM, K=1280 per split j (blocks i=5j..5j+4) ----
__global__ __launch_bounds__(256)
void skipm(const u16* __restrict__ Gh, const u16* __restrict__ SWT,
           float* __restrict__ P) {
  __shared__ u16 As[BM * LDK];
  __shared__ u16 Bs[BN * LDK];

  const int tid = threadIdx.x;
  const int zz = blockIdx.z;
  const int b = zz >> 2, j = zz & 3;
  const int t0 = blockIdx.x * BM;
  const int n0 = blockIdx.y * BN;
  const int lane = tid & 63, wv = tid >> 6;
  const int wm = wv >> 1, wn = wv & 1;
  const int fr = lane & 15, fq = lane >> 4;

  f32x4 acc[4][4];
  #pragma unroll
  for (int fm = 0; fm < 4; ++fm)
    #pragma unroll
    for (int fn = 0; fn < 4; ++fn) acc[fm][fn] = (f32x4){0.f, 0.f, 0.f, 0.f};

  for (int kt = 0; kt < 20; ++kt) {
    int i = j * 5 + (kt >> 2);
    int toff = TOUT[i] - SKL;
    const u16* Gi = Gh + (size_t)i * GSTRIDE + (size_t)b * XSTR;
    for (int idx = tid; idx < 1024; idx += 256) {
      int r = idx >> 3, c8 = idx & 7;
      int t = t0 + r; if (t > SKL - 1) t = SKL - 1;
      const u16* sp = Gi + (size_t)(toff + t) * CCH + (kt & 3) * 64 + c8 * 8;
      *(uint4*)&As[r * LDK + c8 * 8] = *(const uint4*)sp;
    }
    for (int idx = tid; idx < 1024; idx += 256) {
      int r = idx >> 3, c8 = idx & 7;
      const u16* sp = SWT + (size_t)(n0 + r) * 5120 + i * 256 + (kt & 3) * 64 + c8 * 8;
      *(uint4*)&Bs[r * LDK + c8 * 8] = *(const uint4*)sp;
    }
    __syncthreads();

    #pragma unroll
    for (int ks = 0; ks < 2; ++ks) {
      short8 af[4], bfr[4];
      #pragma unroll
      for (int fm = 0; fm < 4; ++fm)
        af[fm] = *(const short8*)&As[(wm * 64 + fm * 16 + fr) * LDK + ks * 32 + fq * 8];
      #pragma unroll
      for (int fn = 0; fn < 4; ++fn)
        bfr[fn] = *(const short8*)&Bs[(wn * 64 + fn * 16 + fr) * LDK + ks * 32 + fq * 8];
      #pragma unroll
      for (int fm = 0; fm < 4; ++fm)
        #pragma unroll
        for (int fn = 0; fn < 4; ++fn)
          acc[fm][fn] = __builtin_amdgcn_mfma_f32_16x16x32_bf16(
              af[fm], bfr[fn], acc[fm][fn], 0, 0, 0);
    }
    __syncthreads();
  }

  float* Pj = P + (size_t)(j * BATCH + b) * SSTR;
  #pragma unroll
  for (int fm = 0; fm < 4; ++fm) {
    int rbase = t0 + wm * 64 + fm * 16 + fq * 4;
    #pragma unroll
    for (int r = 0; r < 4; ++r) {
      int t = rbase + r;
      if (t >= SKL) continue;
      #pragma unroll
      for (int fn = 0; fn < 4; ++fn) {
        int c = n0 + wn * 64 + fn * 16 + fr;
        Pj[(size_t)t * CCH + c] = acc[fm][fn][r];
      }
    }
  }
}

// ---------------- dense head (fp32, memory-bound on 537MB weights) --------
__global__ __launch_bounds__(256)
void dense_partial(const float* __restrict__ f, const float* __restrict__ W,
                   float* __restrict__ part) {
  int tstep = blockIdx.x;
  int n = threadIdx.x;
  __shared__ float fs[BATCH][CCH];
  for (int idx = threadIdx.x; idx < BATCH * CCH; idx += 256) {
    int b = idx >> 8, c = idx & 255;
    fs[b][c] = f[((size_t)b * SKL + tstep) * CCH + c];
  }
  __syncthreads();
  float acc[BATCH] = {0.f, 0.f, 0.f, 0.f, 0.f, 0.f, 0.f, 0.f};
  const float* Wr = W + (size_t)tstep * CCH * CCH;
  for (int ci = 0; ci < CCH; ++ci) {
    float w = Wr[(size_t)ci * CCH + n];
    #pragma unroll
    for (int b = 0; b < BATCH; ++b) acc[b] = fmaf(fs[b][ci], w, acc[b]);
  }
  #pragma unroll
  for (int b = 0; b < BATCH; ++b)
    part[((size_t)tstep * BATCH + b) * CCH + n] = acc[b];
}

__global__ __launch_bounds__(256)
void reduce_part(const float* __restrict__ part, float* __restrict__ part2) {
  int chunk = blockIdx.x, b = blockIdx.y, n = threadIdx.x;
  int c0 = chunk * 33;
  int c1 = c0 + 33; if (c1 > SKL) c1 = SKL;
  float s = 0.f;
  for (int c = c0; c < c1; ++c) s += part[((size_t)c * BATCH + b) * CCH + n];
  part2[((size_t)b * 64 + chunk) * CCH + n] = s;
}

__global__ __launch_bounds__(256)
void softmax_k(const float* __restrict__ part2, const float* __restrict__ db,
               float* __restrict__ out) {
  int b = blockIdx.x, n = threadIdx.x;
  float s = db[n];
  for (int ch = 0; ch < 64; ++ch) s += part2[((size_t)b * 64 + ch) * CCH + n];

  __shared__ float r4[4];
  __shared__ float mglob, sglob;
  int wid = n >> 6, lane = n & 63;

  float m = s;
  #pragma unroll
  for (int off = 1; off < 64; off <<= 1) m = fmaxf(m, __shfl_xor(m, off));
  if (lane == 0) r4[wid] = m;
  __syncthreads();
  if (n == 0) mglob = fmaxf(fmaxf(r4[0], r4[1]), fmaxf(r4[2], r4[3]));
  __syncthreads();

  float e = expf(s - mglob);
  float se = e;
  #pragma unroll
  for (int off = 1; off < 64; off <<= 1) se += __shfl_xor(se, off);
  if (lane == 0) r4[wid] = se;
  __syncthreads();
  if (n == 0) sglob = r4[0] + r4[1] + r4[2] + r4[3];
  __syncthreads();

  out[(size_t)b * CCH + n] = e / sglob;
}

extern "C" void kernel_launch(void* const* d_in, const int* in_sizes, int n_in,
                              void* d_out, int out_size, void* d_ws, size_t ws_size,
                              hipStream_t stream) {
  const float* input_x  = (const float*)d_in[0];
  const float* causal_w = (const float*)d_in[1];
  const float* causal_b = (const float*)d_in[2];
  const float* dil_w    = (const float*)d_in[3];
  const float* dil_b    = (const float*)d_in[4];
  const float* res_w    = (const float*)d_in[5];
  const float* res_b    = (const float*)d_in[6];
  const float* skip_w   = (const float*)d_in[7];
  const float* skip_b   = (const float*)d_in[8];
  const float* cls_w    = (const float*)d_in[9];
  const float* cls_b    = (const float*)d_in[10];
  const float* dense_w  = (const float*)d_in[11];
  const float* dense_b  = (const float*)d_in[12];
  float* out = (float*)d_out;

  // ---- workspace layout ----
  char* p = (char*)d_ws;
  u16*   Gh    = (u16*)p;   p += GSTRIDE * 20 * 2;                 // 335 MB
  float* P     = (float*)p; p += PSTR * 4 * 4;                     // 67 MB
  u16*   S1    = (u16*)p;   p += (size_t)BATCH * SKL * CCH * 2;
  float* S2    = (float*)p; p += (size_t)BATCH * SKL * CCH * 4;
  float* PART  = (float*)p; p += (size_t)SKL * BATCH * CCH * 4;
  float* PART2 = (float*)p; p += (size_t)BATCH * 64 * CCH * 4;
  u16*   DWc   = (u16*)p;   p += (size_t)19 * 256 * 512 * 2;
  float* Bc    = (float*)p; p += (size_t)19 * 256 * 4;
  u16*   SWT   = (u16*)p;   p += (size_t)256 * 5120 * 2;
  u16*   CW    = (u16*)p;   p += (size_t)256 * 256 * 2;
  float* U     = (float*)p; p += (size_t)768 * 4;
  float* SBS   = (float*)p; p += (size_t)256 * 4;

  static const int dil[20] = {1, 2, 4, 8, 16, 32, 64, 128, 256, 512,
                              1, 2, 4, 8, 16, 32, 64, 128, 256, 512};
  static const int tout_h[20] = {4095,4093,4089,4081,4065,4033,3969,3841,3585,3073,
                                 3072,3070,3066,3058,3042,3010,2946,2818,2562,2050};
  dim3 blk(256);

  // weight compose + packs (independent, off the GEMM chain start)
  compose_w   <<<dim3(19 * 2 * 8), blk, 0, stream>>>(res_w, dil_w, DWc);
  compose_bias<<<dim3(19), blk, 0, stream>>>(res_b, dil_w, dil_b, Bc);
  head0       <<<dim3(1), blk, 0, stream>>>(causal_w, causal_b, dil_w, dil_b, U);
  pack_skipT  <<<dim3(20 * 256), blk, 0, stream>>>(skip_w, SWT);
  pack_cls    <<<dim3(256), blk, 0, stream>>>(cls_w, CW);
  sbsum_k     <<<dim3(1), blk, 0, stream>>>(skip_b, SBS);

  // G0 via rank-1 fold (exact fp32)
  g0_init<<<dim3(4095, BATCH), blk, 0, stream>>>(input_x, U, Gh);

  // 19 composed gate GEMMs: G_i = gate(G_{i-1}[t]@W0' + G_{i-1}[t+d]@W1' + b')
  for (int i = 1; i < 20; ++i) {
    int Tout = tout_h[i];
    int ntile = (Tout + BM - 1) / BM;
    convm<2, MODE_GATE><<<dim3(ntile, 2, BATCH), blk, 0, stream>>>(
        Gh + (size_t)(i - 1) * GSTRIDE, XSTR, dil[i],
        DWc + (size_t)(i - 1) * 256 * 512, Bc + (size_t)(i - 1) * 256, nullptr,
        Gh + (size_t)i * GSTRIDE, XSTR, Tout);
  }

  // deferred skip mega-GEMM (K=5120 split x4 into fp32 partials)
  int stile = (SKL + BM - 1) / BM;
  skipm<<<dim3(stile, 2, BATCH * 4), blk, 0, stream>>>(Gh, SWT, P);

  // head: S1 = relu((sum P + sbsum)/20) @ CW + cb ; S2 = relu(S1) @ CW + cb
  convm<1, MODE_CLS1><<<dim3(stile, 2, BATCH), blk, 0, stream>>>(
      P, (long)SSTR, 0, CW, cls_b, SBS, S1, (long)SSTR, SKL);
  convm<1, MODE_CLS2><<<dim3(stile, 2, BATCH), blk, 0, stream>>>(
      S1, (long)SSTR, 0, CW, cls_b, nullptr, S2, (long)SSTR, SKL);

  dense_partial<<<dim3(SKL), blk, 0, stream>>>(S2, dense_w, PART);
  reduce_part<<<dim3(64, BATCH), blk, 0, stream>>>(PART, PART2);
  softmax_k<<<dim3(BATCH), blk, 0, stream>>>(PART2, dense_b, out);
}

// Round 4
// 718.458 us; speedup vs baseline: 8.6851x; 1.4762x over previous
//
#include <hip/hip_runtime.h>

typedef __attribute__((ext_vector_type(8))) short short8;
typedef __attribute__((ext_vector_type(4))) float f32x4;
typedef unsigned int uint32;
typedef unsigned short u16;

#define CCH   256
#define BATCH 8
#define LFULL 4096
#define SKL   2050
#define BM    128
#define BN    128
#define LDK   72   // padded LDS stride for the (cold) reg-staged cls kernel

#define GSTRIDE ((size_t)BATCH * LFULL * CCH)  // elems per G(i) buffer
#define XSTR    ((size_t)LFULL * CCH)          // per-batch stride in G
#define SSTR    ((size_t)SKL * CCH)            // per-batch stride in P/S buffers
#define PSTR    ((size_t)BATCH * SKL * CCH)    // per-split stride in P

__device__ const int TOUT[20] = {4095,4093,4089,4081,4065,4033,3969,3841,3585,3073,
                                 3072,3070,3066,3058,3042,3010,2946,2818,2562,2050};

__device__ __forceinline__ u16 f2b(float f) {
  uint32 u = __float_as_uint(f);
  u += 0x7fff + ((u >> 16) & 1);
  return (u16)(u >> 16);
}
__device__ __forceinline__ float gatef(float h) {
  float hc = fmaxf(h, -30.0f);
  float q = __expf(-hc);
  // tanh(h)*sigmoid(h) = (1-q)/(1+q^2), q=e^-h ; v_rcp_f32 (~1ulp) ok for bf16 out
  return (1.0f - q) * __builtin_amdgcn_rcpf(fmaf(q, q, 1.0f));
}
__device__ __forceinline__ void glds16(const void* g, void* l) {
  __builtin_amdgcn_global_load_lds(
      (const __attribute__((address_space(1))) void*)g,
      (__attribute__((address_space(3))) void*)l, 16, 0, 0);
}

// ---- compose W'_i = (R_{i-1} + I) @ W_i,tap  -> bf16 [bi][co][tap*256+ci] ----
__global__ __launch_bounds__(256)
void compose_w(const float* __restrict__ res_w, const float* __restrict__ dil_w,
               u16* __restrict__ DWc) {
  __shared__ float As[32][256];
  int bx = blockIdx.x;
  int chunk = bx & 7, tap = (bx >> 3) & 1, bi = bx >> 4;  // bi 0..18 -> block i=bi+1
  int i = bi + 1;
  int co = threadIdx.x;
  int ci0 = chunk * 32;

  for (int idx = threadIdx.x; idx < 32 * 256; idx += 256) {
    int r = idx >> 8, m = idx & 255;
    float v = res_w[((size_t)(bi * 256 + ci0 + r)) * 256 + m];
    if (ci0 + r == m) v += 1.0f;
    As[r][m] = v;
  }
  __syncthreads();

  float acc[32];
  #pragma unroll
  for (int r = 0; r < 32; ++r) acc[r] = 0.0f;

  const float* Wb = dil_w + ((size_t)(i * 2 + tap) * 256) * 256 + co;
  for (int m4 = 0; m4 < 64; ++m4) {
    const float* wp = Wb + (size_t)m4 * 4 * 256;
    float w0 = wp[0], w1 = wp[256], w2 = wp[512], w3 = wp[768];
    #pragma unroll
    for (int r = 0; r < 32; ++r) {
      float4 a = *(const float4*)&As[r][m4 * 4];
      acc[r] = fmaf(a.x, w0, acc[r]);
      acc[r] = fmaf(a.y, w1, acc[r]);
      acc[r] = fmaf(a.z, w2, acc[r]);
      acc[r] = fmaf(a.w, w3, acc[r]);
    }
  }
  u16* op = DWc + ((size_t)(bi * 256 + co)) * 512 + tap * 256 + ci0;
  #pragma unroll
  for (int r = 0; r < 32; ++r) op[r] = f2b(acc[r]);
}

// ---- b'_i = rb_{i-1} @ (W0_i + W1_i) + db_i  (fp32) ----
__global__ __launch_bounds__(256)
void compose_bias(const float* __restrict__ res_b, const float* __restrict__ dil_w,
                  const float* __restrict__ dil_b, float* __restrict__ Bc) {
  int bi = blockIdx.x, i = bi + 1, co = threadIdx.x;
  float acc = dil_b[(size_t)i * 256 + co];
  const float* W0 = dil_w + ((size_t)(i * 2 + 0) * 256) * 256;
  const float* W1 = dil_w + ((size_t)(i * 2 + 1) * 256) * 256;
  for (int m = 0; m < 256; ++m) {
    float rb = res_b[(size_t)bi * 256 + m];
    acc = fmaf(rb, W0[(size_t)m * 256 + co] + W1[(size_t)m * 256 + co], acc);
  }
  Bc[(size_t)bi * 256 + co] = acc;
}

// ---- block-0 rank-1 fold ----
__global__ __launch_bounds__(256)
void head0(const float* __restrict__ causal_w, const float* __restrict__ causal_b,
           const float* __restrict__ dil_w, const float* __restrict__ dil_b,
           float* __restrict__ U) {
  int co = threadIdx.x;
  float u0 = 0.f, u1 = 0.f, b0 = dil_b[co];
  for (int m = 0; m < 256; ++m) {
    float cwm = causal_w[m], cbm = causal_b[m];
    float w0 = dil_w[(size_t)m * 256 + co];
    float w1 = dil_w[(size_t)(256 + m) * 256 + co];
    u0 = fmaf(cwm, w0, u0);
    u1 = fmaf(cwm, w1, u1);
    b0 = fmaf(cbm, w0 + w1, b0);
  }
  U[co] = u0; U[256 + co] = u1; U[512 + co] = b0;
}

// ---- G0[b][t][c] = gate(in[t]*u0 + in[t+1]*u1 + b0) ----
__global__ __launch_bounds__(256)
void g0_init(const float* __restrict__ in, const float* __restrict__ U,
             u16* __restrict__ G0) {
  int t = blockIdx.x, b = blockIdx.y, co = threadIdx.x;
  float x0 = in[(size_t)b * LFULL + t];
  float x1 = in[(size_t)b * LFULL + t + 1];
  float h = fmaf(x0, U[co], fmaf(x1, U[256 + co], U[512 + co]));
  G0[((size_t)b * LFULL + t) * CCH + co] = f2b(gatef(h));
}

// ---- weight packs ----
__global__ __launch_bounds__(256)
void pack_skipT(const float* __restrict__ w, u16* __restrict__ o) {
  int e = blockIdx.x * 256 + threadIdx.x;   // (i*256+ci)*256+co
  int co = e & 255, ci = (e >> 8) & 255, i = e >> 16;
  o[(size_t)co * 5120 + i * 256 + ci] = f2b(w[e]);
}
__global__ __launch_bounds__(256)
void pack_cls(const float* __restrict__ w, u16* __restrict__ o) {
  int e = blockIdx.x * 256 + threadIdx.x;   // ci*256+co
  int co = e & 255, ci = e >> 8;
  o[(size_t)co * 256 + ci] = f2b(w[e]);
}
__global__ __launch_bounds__(256)
void sbsum_k(const float* __restrict__ sb, float* __restrict__ o) {
  int n = threadIdx.x;
  float s = 0.f;
  for (int i = 0; i < 20; ++i) s += sb[(size_t)i * 256 + n];
  o[n] = s;
}

// ============ HOT: gate GEMM, global_load_lds + XOR-swizzled ds_read =======
// out[t][n] = gate( A[t][k]@W0'[n][k] + A[t+d][k]@W1'[n][k] + b' )
__global__ __launch_bounds__(256)
void gatem(const u16* __restrict__ Ain, int d,
           const u16* __restrict__ Wt, const float* __restrict__ bias,
           u16* __restrict__ Out1, int Tout) {
  __shared__ u16 As[BM * 64];
  __shared__ u16 Bs[BN * 64];

  const int tid = threadIdx.x;
  const int bb  = blockIdx.z;
  const int t0  = blockIdx.x * BM;
  const int n0  = blockIdx.y * BN;
  const int lane = tid & 63, wv = tid >> 6;
  const int wm = wv >> 1, wn = wv & 1;
  const int fr = lane & 15, fq = lane >> 4;
  const int rl = lane >> 3;                 // row-in-8 for staging
  const int subx = ((lane & 7) ^ rl) * 8;   // source-swizzled 16B chunk (elems)

  const u16* Ab = Ain + (size_t)bb * XSTR;

  f32x4 acc[4][4];
  #pragma unroll
  for (int fn = 0; fn < 4; ++fn) {
    float bv = bias[n0 + wn * 64 + fn * 16 + fr];
    #pragma unroll
    for (int fm = 0; fm < 4; ++fm) acc[fm][fn] = (f32x4){bv, bv, bv, bv};
  }

  for (int kt = 0; kt < 8; ++kt) {
    const int tap = kt >> 2, ks0 = (kt & 3) * 64;
    const int rowb = wv * 32;
    #pragma unroll
    for (int q = 0; q < 4; ++q) {
      int t = t0 + rowb + q * 8 + rl;
      if (t > Tout - 1) t = Tout - 1;               // per-lane clamp (global side)
      glds16(Ab + (size_t)(t + tap * d) * CCH + ks0 + subx,
             As + (rowb + q * 8) * 64);
      glds16(Wt + (size_t)(n0 + rowb + q * 8 + rl) * 512 + kt * 64 + subx,
             Bs + (rowb + q * 8) * 64);
    }
    __syncthreads();

    #pragma unroll
    for (int ks = 0; ks < 2; ++ks) {
      short8 af[4], bfr[4];
      #pragma unroll
      for (int fm = 0; fm < 4; ++fm) {
        int row = wm * 64 + fm * 16 + fr;
        af[fm] = *(const short8*)&As[row * 64 + ((ks * 4 + fq) ^ (row & 7)) * 8];
      }
      #pragma unroll
      for (int fn = 0; fn < 4; ++fn) {
        int row = wn * 64 + fn * 16 + fr;
        bfr[fn] = *(const short8*)&Bs[row * 64 + ((ks * 4 + fq) ^ (row & 7)) * 8];
      }
      #pragma unroll
      for (int fm = 0; fm < 4; ++fm)
        #pragma unroll
        for (int fn = 0; fn < 4; ++fn)
          acc[fm][fn] = __builtin_amdgcn_mfma_f32_16x16x32_bf16(
              af[fm], bfr[fn], acc[fm][fn], 0, 0, 0);
    }
    __syncthreads();
  }

  u16* Ob = Out1 + (size_t)bb * XSTR;
  #pragma unroll
  for (int fm = 0; fm < 4; ++fm) {
    int rbase = t0 + wm * 64 + fm * 16 + fq * 4;
    #pragma unroll
    for (int r = 0; r < 4; ++r) {
      int t = rbase + r;
      if (t >= Tout) continue;
      #pragma unroll
      for (int fn = 0; fn < 4; ++fn) {
        int c = n0 + wn * 64 + fn * 16 + fr;
        Ob[(size_t)t * CCH + c] = f2b(gatef(acc[fm][fn][r]));
      }
    }
  }
}

// ============ HOT: deferred-skip mega-GEMM (K=1280/split), glds staging ====
__global__ __launch_bounds__(256)
void skipm(const u16* __restrict__ Gh, const u16* __restrict__ SWT,
           float* __restrict__ P) {
  __shared__ u16 As[BM * 64];
  __shared__ u16 Bs[BN * 64];

  const int tid = threadIdx.x;
  const int zz = blockIdx.z;
  const int b = zz >> 2, j = zz & 3;
  const int t0 = blockIdx.x * BM;
  const int n0 = blockIdx.y * BN;
  const int lane = tid & 63, wv = tid >> 6;
  const int wm = wv >> 1, wn = wv & 1;
  const int fr = lane & 15, fq = lane >> 4;
  const int rl = lane >> 3;
  const int subx = ((lane & 7) ^ rl) * 8;

  f32x4 acc[4][4];
  #pragma unroll
  for (int fm = 0; fm < 4; ++fm)
    #pragma unroll
    for (int fn = 0; fn < 4; ++fn) acc[fm][fn] = (f32x4){0.f, 0.f, 0.f, 0.f};

  for (int kt = 0; kt < 20; ++kt) {
    const int i = j * 5 + (kt >> 2);
    const int toff = TOUT[i] - SKL;
    const int ks0 = (kt & 3) * 64;
    const u16* Gi = Gh + (size_t)i * GSTRIDE + (size_t)b * XSTR;
    const int rowb = wv * 32;
    #pragma unroll
    for (int q = 0; q < 4; ++q) {
      int t = t0 + rowb + q * 8 + rl;
      if (t > SKL - 1) t = SKL - 1;
      glds16(Gi + (size_t)(toff + t) * CCH + ks0 + subx,
             As + (rowb + q * 8) * 64);
      glds16(SWT + (size_t)(n0 + rowb + q * 8 + rl) * 5120 + i * 256 + ks0 + subx,
             Bs + (rowb + q * 8) * 64);
    }
    __syncthreads();

    #pragma unroll
    for (int ks = 0; ks < 2; ++ks) {
      short8 af[4], bfr[4];
      #pragma unroll
      for (int fm = 0; fm < 4; ++fm) {
        int row = wm * 64 + fm * 16 + fr;
        af[fm] = *(const short8*)&As[row * 64 + ((ks * 4 + fq) ^ (row & 7)) * 8];
      }
      #pragma unroll
      for (int fn = 0; fn < 4; ++fn) {
        int row = wn * 64 + fn * 16 + fr;
        bfr[fn] = *(const short8*)&Bs[row * 64 + ((ks * 4 + fq) ^ (row & 7)) * 8];
      }
      #pragma unroll
      for (int fm = 0; fm < 4; ++fm)
        #pragma unroll
        for (int fn = 0; fn < 4; ++fn)
          acc[fm][fn] = __builtin_amdgcn_mfma_f32_16x16x32_bf16(
              af[fm], bfr[fn], acc[fm][fn], 0, 0, 0);
    }
    __syncthreads();
  }

  float* Pj = P + (size_t)(j * BATCH + b) * SSTR;
  #pragma unroll
  for (int fm = 0; fm < 4; ++fm) {
    int rbase = t0 + wm * 64 + fm * 16 + fq * 4;
    #pragma unroll
    for (int r = 0; r < 4; ++r) {
      int t = rbase + r;
      if (t >= SKL) continue;
      #pragma unroll
      for (int fn = 0; fn < 4; ++fn) {
        int c = n0 + wn * 64 + fn * 16 + fr;
        Pj[(size_t)t * CCH + c] = acc[fm][fn][r];
      }
    }
  }
}

// ============ cold cls GEMMs: reg-staged (transform fused in stage) ========
enum { MODE_CLS1 = 1, MODE_CLS2 = 2 };

template <int MODE>
__global__ __launch_bounds__(256)
void convm(const void* __restrict__ Ainv, long a_bstride,
           const u16* __restrict__ Wt, const float* __restrict__ bias,
           const float* __restrict__ extra,
           void* __restrict__ Out1, long out_bstride, int Tout) {
  __shared__ u16 As[BM * LDK];
  __shared__ u16 Bs[BN * LDK];

  const int tid = threadIdx.x;
  const int bb  = blockIdx.z;
  const int t0  = blockIdx.x * BM;
  const int n0  = blockIdx.y * BN;
  const int lane = tid & 63, wv = tid >> 6;
  const int wm = wv >> 1, wn = wv & 1;
  const int fr = lane & 15, fq = lane >> 4;

  f32x4 acc[4][4];
  #pragma unroll
  for (int fn = 0; fn < 4; ++fn) {
    float bv = bias[n0 + wn * 64 + fn * 16 + fr];
    #pragma unroll
    for (int fm = 0; fm < 4; ++fm) acc[fm][fn] = (f32x4){bv, bv, bv, bv};
  }

  for (int kt = 0; kt < 4; ++kt) {
    for (int idx = tid; idx < 1024; idx += 256) {
      int r = idx >> 3, c8 = idx & 7;
      int t = t0 + r; if (t > Tout - 1) t = Tout - 1;
      uint4 v;
      if constexpr (MODE == MODE_CLS1) {
        const float* p0 = (const float*)Ainv + (size_t)bb * a_bstride +
                          (size_t)t * CCH + kt * 64 + c8 * 8;
        float4 s0 = *(const float4*)p0;
        float4 s1 = *(const float4*)(p0 + 4);
        #pragma unroll
        for (int jj = 1; jj < 4; ++jj) {
          const float* pj = p0 + (size_t)jj * PSTR;
          float4 a0 = *(const float4*)pj;
          float4 a1 = *(const float4*)(pj + 4);
          s0.x += a0.x; s0.y += a0.y; s0.z += a0.z; s0.w += a0.w;
          s1.x += a1.x; s1.y += a1.y; s1.z += a1.z; s1.w += a1.w;
        }
        float4 e0 = *(const float4*)&extra[kt * 64 + c8 * 8];
        float4 e1 = *(const float4*)&extra[kt * 64 + c8 * 8 + 4];
        u16 tmp[8];
        tmp[0] = f2b(fmaxf((s0.x + e0.x) * 0.05f, 0.f));
        tmp[1] = f2b(fmaxf((s0.y + e0.y) * 0.05f, 0.f));
        tmp[2] = f2b(fmaxf((s0.z + e0.z) * 0.05f, 0.f));
        tmp[3] = f2b(fmaxf((s0.w + e0.w) * 0.05f, 0.f));
        tmp[4] = f2b(fmaxf((s1.x + e1.x) * 0.05f, 0.f));
        tmp[5] = f2b(fmaxf((s1.y + e1.y) * 0.05f, 0.f));
        tmp[6] = f2b(fmaxf((s1.z + e1.z) * 0.05f, 0.f));
        tmp[7] = f2b(fmaxf((s1.w + e1.w) * 0.05f, 0.f));
        v = *(uint4*)tmp;
      } else {
        const u16* sp = (const u16*)Ainv + (size_t)bb * a_bstride +
                        (size_t)t * CCH + kt * 64 + c8 * 8;
        uint4 raw = *(const uint4*)sp;
        u16 tmp[8];
        *(uint4*)tmp = raw;
        #pragma unroll
        for (int jj = 0; jj < 8; ++jj) tmp[jj] = (tmp[jj] & 0x8000) ? (u16)0 : tmp[jj];
        v = *(uint4*)tmp;
      }
      *(uint4*)&As[r * LDK + c8 * 8] = v;
    }
    for (int idx = tid; idx < 1024; idx += 256) {
      int r = idx >> 3, c8 = idx & 7;
      const u16* sp = Wt + (size_t)(n0 + r) * 256 + kt * 64 + c8 * 8;
      *(uint4*)&Bs[r * LDK + c8 * 8] = *(const uint4*)sp;
    }
    __syncthreads();

    #pragma unroll
    for (int ks = 0; ks < 2; ++ks) {
      short8 af[4], bfr[4];
      #pragma unroll
      for (int fm = 0; fm < 4; ++fm)
        af[fm] = *(const short8*)&As[(wm * 64 + fm * 16 + fr) * LDK + ks * 32 + fq * 8];
      #pragma unroll
      for (int fn = 0; fn < 4; ++fn)
        bfr[fn] = *(const short8*)&Bs[(wn * 64 + fn * 16 + fr) * LDK + ks * 32 + fq * 8];
      #pragma unroll
      for (int fm = 0; fm < 4; ++fm)
        #pragma unroll
        for (int fn = 0; fn < 4; ++fn)
          acc[fm][fn] = __builtin_amdgcn_mfma_f32_16x16x32_bf16(
              af[fm], bfr[fn], acc[fm][fn], 0, 0, 0);
    }
    __syncthreads();
  }

  #pragma unroll
  for (int fm = 0; fm < 4; ++fm) {
    int rbase = t0 + wm * 64 + fm * 16 + fq * 4;
    #pragma unroll
    for (int r = 0; r < 4; ++r) {
      int t = rbase + r;
      if (t >= Tout) continue;
      #pragma unroll
      for (int fn = 0; fn < 4; ++fn) {
        int c = n0 + wn * 64 + fn * 16 + fr;
        float a = acc[fm][fn][r];
        size_t oix = (size_t)bb * out_bstride + (size_t)t * CCH + c;
        if constexpr (MODE == MODE_CLS1) {
          ((u16*)Out1)[oix] = f2b(a);
        } else {
          ((float*)Out1)[oix] = a;
        }
      }
    }
  }
}

// ---------------- dense head (fp32, memory-bound on 537MB weights) --------
__global__ __launch_bounds__(256)
void dense_partial(const float* __restrict__ f, const float* __restrict__ W,
                   float* __restrict__ part) {
  int tstep = blockIdx.x;
  int n = threadIdx.x;
  __shared__ float fs[BATCH][CCH];
  for (int idx = threadIdx.x; idx < BATCH * CCH; idx += 256) {
    int b = idx >> 8, c = idx & 255;
    fs[b][c] = f[((size_t)b * SKL + tstep) * CCH + c];
  }
  __syncthreads();
  float acc[BATCH] = {0.f, 0.f, 0.f, 0.f, 0.f, 0.f, 0.f, 0.f};
  const float* Wr = W + (size_t)tstep * CCH * CCH;
  for (int ci = 0; ci < CCH; ++ci) {
    float w = Wr[(size_t)ci * CCH + n];
    #pragma unroll
    for (int b = 0; b < BATCH; ++b) acc[b] = fmaf(fs[b][ci], w, acc[b]);
  }
  #pragma unroll
  for (int b = 0; b < BATCH; ++b)
    part[((size_t)tstep * BATCH + b) * CCH + n] = acc[b];
}

__global__ __launch_bounds__(256)
void reduce_part(const float* __restrict__ part, float* __restrict__ part2) {
  int chunk = blockIdx.x, b = blockIdx.y, n = threadIdx.x;
  int c0 = chunk * 33;
  int c1 = c0 + 33; if (c1 > SKL) c1 = SKL;
  float s = 0.f;
  for (int c = c0; c < c1; ++c) s += part[((size_t)c * BATCH + b) * CCH + n];
  part2[((size_t)b * 64 + chunk) * CCH + n] = s;
}

__global__ __launch_bounds__(256)
void softmax_k(const float* __restrict__ part2, const float* __restrict__ db,
               float* __restrict__ out) {
  int b = blockIdx.x, n = threadIdx.x;
  float s = db[n];
  for (int ch = 0; ch < 64; ++ch) s += part2[((size_t)b * 64 + ch) * CCH + n];

  __shared__ float r4[4];
  __shared__ float mglob, sglob;
  int wid = n >> 6, lane = n & 63;

  float m = s;
  #pragma unroll
  for (int off = 1; off < 64; off <<= 1) m = fmaxf(m, __shfl_xor(m, off));
  if (lane == 0) r4[wid] = m;
  __syncthreads();
  if (n == 0) mglob = fmaxf(fmaxf(r4[0], r4[1]), fmaxf(r4[2], r4[3]));
  __syncthreads();

  float e = expf(s - mglob);
  float se = e;
  #pragma unroll
  for (int off = 1; off < 64; off <<= 1) se += __shfl_xor(se, off);
  if (lane == 0) r4[wid] = se;
  __syncthreads();
  if (n == 0) sglob = r4[0] + r4[1] + r4[2] + r4[3];
  __syncthreads();

  out[(size_t)b * CCH + n] = e / sglob;
}

extern "C" void kernel_launch(void* const* d_in, const int* in_sizes, int n_in,
                              void* d_out, int out_size, void* d_ws, size_t ws_size,
                              hipStream_t stream) {
  const float* input_x  = (const float*)d_in[0];
  const float* causal_w = (const float*)d_in[1];
  const float* causal_b = (const float*)d_in[2];
  const float* dil_w    = (const float*)d_in[3];
  const float* dil_b    = (const float*)d_in[4];
  const float* res_w    = (const float*)d_in[5];
  const float* res_b    = (const float*)d_in[6];
  const float* skip_w   = (const float*)d_in[7];
  const float* skip_b   = (const float*)d_in[8];
  const float* cls_w    = (const float*)d_in[9];
  const float* cls_b    = (const float*)d_in[10];
  const float* dense_w  = (const float*)d_in[11];
  const float* dense_b  = (const float*)d_in[12];
  float* out = (float*)d_out;

  // ---- workspace layout ----
  char* p = (char*)d_ws;
  u16*   Gh    = (u16*)p;   p += GSTRIDE * 20 * 2;                 // 335 MB
  float* P     = (float*)p; p += PSTR * 4 * 4;                     // 67 MB
  u16*   S1    = (u16*)p;   p += (size_t)BATCH * SKL * CCH * 2;
  float* S2    = (float*)p; p += (size_t)BATCH * SKL * CCH * 4;
  float* PART  = (float*)p; p += (size_t)SKL * BATCH * CCH * 4;
  float* PART2 = (float*)p; p += (size_t)BATCH * 64 * CCH * 4;
  u16*   DWc   = (u16*)p;   p += (size_t)19 * 256 * 512 * 2;
  float* Bc    = (float*)p; p += (size_t)19 * 256 * 4;
  u16*   SWT   = (u16*)p;   p += (size_t)256 * 5120 * 2;
  u16*   CW    = (u16*)p;   p += (size_t)256 * 256 * 2;
  float* U     = (float*)p; p += (size_t)768 * 4;
  float* SBS   = (float*)p; p += (size_t)256 * 4;

  static const int dil[20] = {1, 2, 4, 8, 16, 32, 64, 128, 256, 512,
                              1, 2, 4, 8, 16, 32, 64, 128, 256, 512};
  static const int tout_h[20] = {4095,4093,4089,4081,4065,4033,3969,3841,3585,3073,
                                 3072,3070,3066,3058,3042,3010,2946,2818,2562,2050};
  dim3 blk(256);

  compose_w   <<<dim3(19 * 2 * 8), blk, 0, stream>>>(res_w, dil_w, DWc);
  compose_bias<<<dim3(19), blk, 0, stream>>>(res_b, dil_w, dil_b, Bc);
  head0       <<<dim3(1), blk, 0, stream>>>(causal_w, causal_b, dil_w, dil_b, U);
  pack_skipT  <<<dim3(20 * 256), blk, 0, stream>>>(skip_w, SWT);
  pack_cls    <<<dim3(256), blk, 0, stream>>>(cls_w, CW);
  sbsum_k     <<<dim3(1), blk, 0, stream>>>(skip_b, SBS);

  g0_init<<<dim3(4095, BATCH), blk, 0, stream>>>(input_x, U, Gh);

  for (int i = 1; i < 20; ++i) {
    int Tout = tout_h[i];
    int ntile = (Tout + BM - 1) / BM;
    gatem<<<dim3(ntile, 2, BATCH), blk, 0, stream>>>(
        Gh + (size_t)(i - 1) * GSTRIDE, dil[i],
        DWc + (size_t)(i - 1) * 256 * 512, Bc + (size_t)(i - 1) * 256,
        Gh + (size_t)i * GSTRIDE, Tout);
  }

  int stile = (SKL + BM - 1) / BM;
  skipm<<<dim3(stile, 2, BATCH * 4), blk, 0, stream>>>(Gh, SWT, P);

  convm<MODE_CLS1><<<dim3(stile, 2, BATCH), blk, 0, stream>>>(
      P, (long)SSTR, CW, cls_b, SBS, S1, (long)SSTR, SKL);
  convm<MODE_CLS2><<<dim3(stile, 2, BATCH), blk, 0, stream>>>(
      S1, (long)SSTR, CW, cls_b, nullptr, S2, (long)SSTR, SKL);

  dense_partial<<<dim3(SKL), blk, 0, stream>>>(S2, dense_w, PART);
  reduce_part<<<dim3(64, BATCH), blk, 0, stream>>>(PART, PART2);
  softmax_k<<<dim3(BATCH), blk, 0, stream>>>(PART2, dense_b, out);
}